// Round 10
// baseline (280.523 us; speedup 1.0000x reference)
//
#include <hip/hip_runtime.h>
#include <hip/hip_bf16.h>
#include <math.h>

#define NN     50000
#define FIN    128
#define F1     64      // H1*C1 = layer-1 output features
#define NH1    8
#define F2     64      // layer-2 output features

#define BSH    256                         // nodes per dst bucket (CSR build)
#define NB     ((NN + BSH - 1) / BSH)      // 196 buckets
#define BCAP   9472                        // per-bucket edge cap (mean 8448, +11 sigma)

typedef __bf16 bf16x8 __attribute__((ext_vector_type(8)));
typedef float  f32x4  __attribute__((ext_vector_type(4)));

// ---------------- runtime dtype helpers ----------------
// flags[0] = 1 if float tensors are fp32 (else bf16)
// flags[1] = 1 if edge_index is int64 (else int32)

__device__ __forceinline__ float loadF(const void* p, long long i, int fp32) {
    if (fp32) return ((const float*)p)[i];
    return __bfloat162float(((const __hip_bfloat16*)p)[i]);
}
__device__ __forceinline__ int loadI_nt(const void* p, long long i, int i64) {
    if (i64) return (int)__builtin_nontemporal_load(&((const long long*)p)[i]);
    return __builtin_nontemporal_load(&((const int*)p)[i]);
}
__device__ __forceinline__ unsigned short f2bfu(float f) {   // RNE f32->bf16 bits
    unsigned u = __float_as_uint(f);
    return (unsigned short)((u + 0x7FFFu + ((u >> 16) & 1u)) >> 16);
}
__device__ __forceinline__ float b2f(unsigned short u) {
    return __uint_as_float(((unsigned)u) << 16);
}

// ---------------- combined sniff + weight pre-swizzle (1 block) ----------------

__global__ void k_pre(const void* __restrict__ x, const void* __restrict__ ei,
                      int* __restrict__ flags,
                      const void* __restrict__ W1, const void* __restrict__ W2,
                      unsigned short* __restrict__ W1p, unsigned short* __restrict__ W2p) {
    __shared__ int s_nanexp, s_oddnz, s_fp32;
    if (threadIdx.x == 0) { s_nanexp = 0; s_oddnz = 0; }
    __syncthreads();
    const unsigned short* u = (const unsigned short*)x;
    int cnt = 0;
    for (int i = threadIdx.x; i < 8192; i += 256) {
        unsigned short v = u[i];
        if ((v & 0x7F80) == 0x7F80) cnt++;         // bf16 Inf/NaN bit pattern
    }
    if (cnt) atomicAdd(&s_nanexp, cnt);
    const unsigned* e32 = (const unsigned*)ei;
    int nz = 0;
    for (int i = threadIdx.x; i < 2048; i += 256) {
        if (e32[2 * i + 1] != 0u) nz++;            // high words if int64
    }
    if (nz) atomicAdd(&s_oddnz, nz);
    __syncthreads();
    if (threadIdx.x == 0) {
        s_fp32 = (s_nanexp > 2) ? 1 : 0;
        flags[0] = s_fp32;
        flags[1] = (s_oddnz == 0) ? 1 : 0;
    }
    __syncthreads();
    int fp32 = s_fp32;
    for (int i = threadIdx.x; i < (FIN / 32) * 4 * 512; i += 256) {   // 8192
        int j = i & 7, l = (i >> 3) & 63, f = i >> 9;
        int kb = f >> 2, nt = f & 3;
        int k = kb * 32 + (l >> 4) * 8 + j, n = nt * 16 + (l & 15);
        W1p[i] = f2bfu(loadF(W1, k * 64 + n, fp32));
    }
    for (int i = threadIdx.x; i < (F1 / 32) * 4 * 512; i += 256) {    // 4096
        int j = i & 7, l = (i >> 3) & 63, f = i >> 9;
        int kb = f >> 2, nt = f & 3;
        int k = kb * 32 + (l >> 4) * 8 + j, n = nt * 16 + (l & 15);
        W2p[i] = f2bfu(loadF(W2, k * 64 + n, fp32));
    }
}

// ---------------- CSR build: bucket bin + per-block LDS counting sort ----

__global__ __launch_bounds__(256) void k_bin_fine(
    const void* __restrict__ ei, int E, int Etot,
    int* __restrict__ bcnt, unsigned* __restrict__ binned,
    const int* __restrict__ flags) {
    int i64 = flags[1];
    __shared__ int hist[NB], gbase[NB];
    for (int i = threadIdx.x; i < NB; i += 256) hist[i] = 0;
    __syncthreads();
    long long base = (long long)blockIdx.x * 4096;
    unsigned pk[16]; short bb[16];
    #pragma unroll
    for (int u = 0; u < 16; ++u) {
        long long j = base + u * 256 + threadIdx.x;
        int s = -1, d = -1;
        if (j < Etot) {
            if (j < E) { s = loadI_nt(ei, j, i64); d = loadI_nt(ei, (long long)E + j, i64); }
            else       { s = d = (int)(j - E); }
        }
        if ((unsigned)s < NN && (unsigned)d < NN) {
            bb[u] = (short)(d >> 8);
            pk[u] = ((unsigned)s << 8) | (unsigned)(d & 255);
            atomicAdd(&hist[bb[u]], 1);
        } else bb[u] = -1;
    }
    __syncthreads();
    for (int i = threadIdx.x; i < NB; i += 256) {
        int h = hist[i];
        gbase[i] = h ? atomicAdd(&bcnt[i], h) : 0;
        hist[i] = 0;                                 // reuse as local cursor
    }
    __syncthreads();
    #pragma unroll
    for (int u = 0; u < 16; ++u) {
        if (bb[u] >= 0) {
            int pos = gbase[bb[u]] + atomicAdd(&hist[bb[u]], 1);
            if (pos < BCAP) binned[(size_t)bb[u] * BCAP + pos] = pk[u];
        }
    }
}

__global__ __launch_bounds__(256) void k_csr_local(
    const int* __restrict__ bcnt, const unsigned* __restrict__ binned,
    int* __restrict__ offs, int* __restrict__ perm) {
    __shared__ int hist[BSH], cur[BSH], sd[BSH];
    int bk = blockIdx.x, tid = threadIdx.x;
    int n0 = bk * BSH;
    // phase 0: prefix over the 196 bucket counts
    int pv = (tid < NB) ? min(bcnt[tid], BCAP) : 0;
    sd[tid] = pv;
    __syncthreads();
    #pragma unroll
    for (int off = 1; off < BSH; off <<= 1) {
        int t = (tid >= off) ? sd[tid - off] : 0;
        __syncthreads();
        sd[tid] += t;
        __syncthreads();
    }
    int gb = (bk > 0) ? sd[bk - 1] : 0;
    if (bk == 0 && tid == 0) offs[NN] = sd[NB - 1];
    __syncthreads();
    // phase 1: histogram of dst&255 within bucket
    int cnt = bcnt[bk]; if (cnt > BCAP) cnt = BCAP;
    const unsigned* bp = binned + (size_t)bk * BCAP;
    hist[tid] = 0;
    __syncthreads();
    for (int i = tid; i < cnt; i += 256)
        atomicAdd(&hist[bp[i] & 255], 1);
    __syncthreads();
    int myh = hist[tid];
    sd[tid] = myh;
    __syncthreads();
    #pragma unroll
    for (int off = 1; off < BSH; off <<= 1) {
        int t = (tid >= off) ? sd[tid - off] : 0;
        __syncthreads();
        sd[tid] += t;
        __syncthreads();
    }
    int excl = sd[tid] - myh;
    cur[tid] = gb + excl;
    if (n0 + tid < NN) offs[n0 + tid] = gb + excl;
    __syncthreads();
    for (int i = tid; i < cnt; i += 256) {
        unsigned pk = bp[i];
        int pos = atomicAdd(&cur[pk & 255], 1);
        perm[pos] = (int)(pk >> 8);
    }
}

// ---------------- MFMA GEMM (layer 1): h1 = x @ W1, + a1s/a1d ----------------

__global__ __launch_bounds__(256) void k_mgemm1(
    const void* __restrict__ x, const unsigned short* __restrict__ W1p,
    const void* __restrict__ attS, const void* __restrict__ attD,
    __hip_bfloat16* __restrict__ h1, _Float16* __restrict__ a1s,
    float* __restrict__ a1d, const int* __restrict__ flags) {
    int fp32 = flags[0];
    __shared__ unsigned short hl[64 * 64];   // 8 KB, bf16 bits
    __shared__ float attSl[64], attDl[64];
    int tid = threadIdx.x;
    if (tid < 64) { attSl[tid] = loadF(attS, tid, fp32); attDl[tid] = loadF(attD, tid, fp32); }
    int w = tid >> 6, l = tid & 63;
    int quad = l >> 4, lm = l & 15;
    int n0 = blockIdx.x * 64;

    bf16x8 bfr[16];
    #pragma unroll
    for (int f = 0; f < 16; ++f)
        bfr[f] = *(const bf16x8*)(W1p + f * 512 + l * 8);

    int nodeA = n0 + w * 16 + lm;
    long long rowA = (nodeA < NN) ? nodeA : 0;     // clamp; garbage unused
    f32x4 acc[4];
    #pragma unroll
    for (int nt = 0; nt < 4; ++nt) acc[nt] = (f32x4){0.f, 0.f, 0.f, 0.f};

    #pragma unroll
    for (int kb = 0; kb < 4; ++kb) {
        bf16x8 af;
        if (!fp32) {
            af = *(const bf16x8*)((const unsigned short*)x + rowA * FIN + kb * 32 + quad * 8);
        } else {
            const float* xf = (const float*)x + rowA * FIN + kb * 32 + quad * 8;
            union { unsigned short s[8]; bf16x8 v; } tmp;
            #pragma unroll
            for (int j = 0; j < 8; ++j) tmp.s[j] = f2bfu(xf[j]);
            af = tmp.v;
        }
        #pragma unroll
        for (int nt = 0; nt < 4; ++nt)
            acc[nt] = __builtin_amdgcn_mfma_f32_16x16x32_bf16(af, bfr[kb * 4 + nt], acc[nt], 0, 0, 0);
    }

    #pragma unroll
    for (int nt = 0; nt < 4; ++nt) {
        #pragma unroll
        for (int r = 0; r < 4; ++r) {
            int nl = w * 16 + quad * 4 + r;
            int node = n0 + nl;
            int c = nt * 16 + lm;
            unsigned short hb = f2bfu(acc[nt][r]);
            hl[nl * 64 + c] = hb;
            if (node < NN) ((unsigned short*)h1)[(size_t)node * 64 + c] = hb;
        }
    }
    __syncthreads();
    // a1s/a1d per (node, head): 64 nodes x 8 heads = 512 pairs
    #pragma unroll
    for (int pp = 0; pp < 2; ++pp) {
        int p = tid + pp * 256;
        int nl = p >> 3, g = p & 7;
        int node = n0 + nl;
        float ss = 0.f, dd = 0.f;
        #pragma unroll
        for (int j = 0; j < 8; ++j) {
            float hv = b2f(hl[nl * 64 + g * 8 + j]);
            ss += hv * attSl[g * 8 + j];
            dd += hv * attDl[g * 8 + j];
        }
        if (node < NN) {
            a1s[(size_t)node * NH1 + g] = (_Float16)ss;
            a1d[(size_t)node * NH1 + g] = dd;
        }
    }
}

// ---------------- MFMA GEMM (layer 2): h2 = helu @ W2, + a2s/a2d ----------------

__global__ __launch_bounds__(256) void k_mgemm2(
    const __hip_bfloat16* __restrict__ helu, const unsigned short* __restrict__ W2p,
    const void* __restrict__ attS, const void* __restrict__ attD,
    __hip_bfloat16* __restrict__ h2, _Float16* __restrict__ a2s,
    float* __restrict__ a2d, const int* __restrict__ flags) {
    int fp32 = flags[0];
    __shared__ unsigned short hl[64 * 64];   // 8 KB
    __shared__ float attSl[64], attDl[64];
    __shared__ float sp[64 * 8], dp[64 * 8];
    int tid = threadIdx.x;
    if (tid < 64) { attSl[tid] = loadF(attS, tid, fp32); attDl[tid] = loadF(attD, tid, fp32); }
    int w = tid >> 6, l = tid & 63;
    int quad = l >> 4, lm = l & 15;
    int n0 = blockIdx.x * 64;

    bf16x8 bfr[8];
    #pragma unroll
    for (int f = 0; f < 8; ++f)
        bfr[f] = *(const bf16x8*)(W2p + f * 512 + l * 8);

    int nodeA = n0 + w * 16 + lm;
    long long rowA = (nodeA < NN) ? nodeA : 0;
    f32x4 acc[4];
    #pragma unroll
    for (int nt = 0; nt < 4; ++nt) acc[nt] = (f32x4){0.f, 0.f, 0.f, 0.f};

    #pragma unroll
    for (int kb = 0; kb < 2; ++kb) {
        bf16x8 af = *(const bf16x8*)((const unsigned short*)helu + rowA * F1 + kb * 32 + quad * 8);
        #pragma unroll
        for (int nt = 0; nt < 4; ++nt)
            acc[nt] = __builtin_amdgcn_mfma_f32_16x16x32_bf16(af, bfr[kb * 4 + nt], acc[nt], 0, 0, 0);
    }

    #pragma unroll
    for (int nt = 0; nt < 4; ++nt) {
        #pragma unroll
        for (int r = 0; r < 4; ++r) {
            int nl = w * 16 + quad * 4 + r;
            int node = n0 + nl;
            int c = nt * 16 + lm;
            unsigned short hb = f2bfu(acc[nt][r]);
            hl[nl * 64 + c] = hb;
            if (node < NN) ((unsigned short*)h2)[(size_t)node * 64 + c] = hb;
        }
    }
    __syncthreads();
    #pragma unroll
    for (int pp = 0; pp < 2; ++pp) {
        int p = tid + pp * 256;
        int nl = p >> 3, g = p & 7;
        float ss = 0.f, dd = 0.f;
        #pragma unroll
        for (int j = 0; j < 8; ++j) {
            float hv = b2f(hl[nl * 64 + g * 8 + j]);
            ss += hv * attSl[g * 8 + j];
            dd += hv * attDl[g * 8 + j];
        }
        sp[nl * 8 + g] = ss;
        dp[nl * 8 + g] = dd;
    }
    __syncthreads();
    if (tid < 64) {
        int node = n0 + tid;
        if (node < NN) {
            float ss = 0.f, dd = 0.f;
            #pragma unroll
            for (int g = 0; g < 8; ++g) { ss += sp[tid * 8 + g]; dd += dp[tid * 8 + g]; }
            a2s[node] = (_Float16)ss;
            a2d[node] = dd;
        }
    }
}

// ---------------- Layer 1 aggregation: dword-paired + pipelined ----------------
// Wave = 1 dst. Phase A: lane (u=c&7, h=c>>3) computes p(edge u, head h) once.
// Commit: lanes split in 2 halves; lane i of half q loads a dword (2 bf16 ch)
// of src row for edge 2k+q -> one global_load_dword covers 2 edges. Next
// batch's perm/a1s prefetched during commit.

__global__ __launch_bounds__(256) void k_agg1(
    const int* __restrict__ offs, const int* __restrict__ perm,
    const __hip_bfloat16* __restrict__ h1, const _Float16* __restrict__ a1s,
    const float* __restrict__ a1d, const void* __restrict__ b1,
    __hip_bfloat16* __restrict__ helu, int n, const int* __restrict__ flags) {
    int fp32 = flags[0];
    int w = threadIdx.x >> 6, c = threadIdx.x & 63;
    int d = blockIdx.x * 4 + w;
    if (d >= n) return;
    int start = offs[d], end = offs[d + 1];
    int u = c & 7, h = c >> 3;
    int half = c >> 5, i = c & 31;
    int pl = ((i >> 2) << 3) + half;                 // lane of p(edge=half, my head-pair)
    float adl = a1d[(size_t)d * NH1 + h];
    const unsigned* hu32 = (const unsigned*)h1;
    float ax = 0.f, ay = 0.f, denp = 0.f;

    int j0 = start + u;
    int sj = perm[(j0 < end) ? j0 : (end - 1)];
    float as = (float)a1s[(size_t)sj * NH1 + h];

    for (int ib = start; ib < end; ib += 8) {
        float e = as + adl;
        e = fmaxf(e, 0.2f * e);                      // leaky_relu(0.2)
        float p = (ib + u < end) ? __expf(e) : 0.f;
        denp += p;
        // prefetch next batch
        int sjn = sj; float asn = as;
        if (ib + 8 < end) {
            int jn = ib + 8 + u;
            sjn = perm[(jn < end) ? jn : (end - 1)];
            asn = (float)a1s[(size_t)sjn * NH1 + h];
        }
        // commit current batch: 4 k-steps x 2 edges
        #pragma unroll
        for (int k = 0; k < 4; ++k) {
            int s0 = __builtin_amdgcn_readlane(sj, 2 * k);
            int s1 = __builtin_amdgcn_readlane(sj, 2 * k + 1);
            int su = half ? s1 : s0;
            unsigned hv = hu32[((unsigned)su << 5) + (unsigned)i];
            float pk = __shfl(p, pl + 2 * k, 64);
            ax = fmaf(pk, __uint_as_float(hv << 16), ax);
            ay = fmaf(pk, __uint_as_float(hv & 0xFFFF0000u), ay);
        }
        sj = sjn; as = asn;
    }
    // den per head (sum over u within each head group)
    denp += __shfl_xor(denp, 1, 64);
    denp += __shfl_xor(denp, 2, 64);
    denp += __shfl_xor(denp, 4, 64);
    float den = __shfl(denp, (i >> 2) << 3, 64) + 1e-16f;
    // combine halves (each accumulated a disjoint edge subset of same channels)
    ax += __shfl_xor(ax, 32, 64);
    ay += __shfl_xor(ay, 32, 64);
    float v0 = ax / den + loadF(b1, 2 * i, fp32);
    float v1 = ay / den + loadF(b1, 2 * i + 1, fp32);
    v0 = (v0 > 0.f) ? v0 : expm1f(v0);               // ELU
    v1 = (v1 > 0.f) ? v1 : expm1f(v1);
    if (c < 32)
        ((unsigned*)helu)[(size_t)d * 32 + i] =
            (unsigned)f2bfu(v0) | ((unsigned)f2bfu(v1) << 16);
}

// ---------------- Layer 2 aggregation + final linear (dword-paired) ----------------

__global__ __launch_bounds__(256) void k_agg2(
    const int* __restrict__ offs, const int* __restrict__ perm,
    const __hip_bfloat16* __restrict__ h2, const _Float16* __restrict__ a2s,
    const float* __restrict__ a2d, const void* __restrict__ b2,
    const void* __restrict__ linW, const void* __restrict__ linb,
    void* __restrict__ out, int n, const int* __restrict__ flags) {
    int fp32 = flags[0];
    int w = threadIdx.x >> 6, c = threadIdx.x & 63;
    int d = blockIdx.x * 4 + w;
    if (d >= n) return;
    int start = offs[d], end = offs[d + 1];
    int u = c & 7;
    int half = c >> 5, i = c & 31;
    float ad = a2d[d];
    const unsigned* hu32 = (const unsigned*)h2;
    float ax = 0.f, ay = 0.f, denp = 0.f;

    int j0 = start + u;
    int sj = perm[(j0 < end) ? j0 : (end - 1)];
    float as = (float)a2s[sj];

    for (int ib = start; ib < end; ib += 8) {
        float e = as + ad;
        e = fmaxf(e, 0.2f * e);
        float p = (ib + u < end) ? __expf(e) : 0.f;
        denp += (c < 8) ? p : 0.f;                   // dedup (p duplicated across groups)
        int sjn = sj; float asn = as;
        if (ib + 8 < end) {
            int jn = ib + 8 + u;
            sjn = perm[(jn < end) ? jn : (end - 1)];
            asn = (float)a2s[sjn];
        }
        #pragma unroll
        for (int k = 0; k < 4; ++k) {
            int s0 = __builtin_amdgcn_readlane(sj, 2 * k);
            int s1 = __builtin_amdgcn_readlane(sj, 2 * k + 1);
            int su = half ? s1 : s0;
            unsigned hv = hu32[((unsigned)su << 5) + (unsigned)i];
            float p0 = __uint_as_float(__builtin_amdgcn_readlane(__float_as_uint(p), 2 * k));
            float p1 = __uint_as_float(__builtin_amdgcn_readlane(__float_as_uint(p), 2 * k + 1));
            float pk = half ? p1 : p0;
            ax = fmaf(pk, __uint_as_float(hv << 16), ax);
            ay = fmaf(pk, __uint_as_float(hv & 0xFFFF0000u), ay);
        }
        sj = sjn; as = asn;
    }
    #pragma unroll
    for (int off = 1; off < 64; off <<= 1) denp += __shfl_xor(denp, off, 64);
    float den = denp + 1e-16f;
    ax += __shfl_xor(ax, 32, 64);
    ay += __shfl_xor(ay, 32, 64);
    float v0 = ax / den + loadF(b2, 2 * i, fp32);
    float v1 = ay / den + loadF(b2, 2 * i + 1, fp32);
    float part = 0.f;
    if (c < 32)
        part = v0 * loadF(linW, 2 * i, fp32) + v1 * loadF(linW, 2 * i + 1, fp32);
    #pragma unroll
    for (int off = 1; off < 64; off <<= 1) part += __shfl_xor(part, off, 64);
    if (c == 0) {
        float r = part + loadF(linb, 0, fp32);
        if (fp32) ((float*)out)[d] = r;
        else      ((__hip_bfloat16*)out)[d] = __float2bfloat16(r);
    }
}

// ---------------- host launcher ----------------

static inline char* carve(char*& p, size_t bytes) {
    char* r = p;
    p += (bytes + 255) & ~size_t(255);
    return r;
}

extern "C" void kernel_launch(void* const* d_in, const int* in_sizes, int n_in,
                              void* d_out, int out_size, void* d_ws, size_t ws_size,
                              hipStream_t stream) {
    const void* x     = d_in[0];
    const void* ei    = d_in[1];
    const void* W1    = d_in[2];
    const void* attS1 = d_in[3];
    const void* attD1 = d_in[4];
    const void* b1    = d_in[5];
    const void* W2    = d_in[6];
    const void* attS2 = d_in[7];
    const void* attD2 = d_in[8];
    const void* b2    = d_in[9];
    const void* linW  = d_in[10];
    const void* linb  = d_in[11];

    int E    = in_sizes[1] / 2;
    int Etot = E + NN;

    // workspace layout (~22 MB)
    char* p = (char*)d_ws;
    int*   flags = (int*)carve(p, 256);
    int*   bcnt  = (int*)carve(p, (size_t)NB * 4);
    unsigned short* W1p = (unsigned short*)carve(p, 8192 * 2);
    unsigned short* W2p = (unsigned short*)carve(p, 4096 * 2);
    int*   offs  = (int*)carve(p, (size_t)(NN + 1) * 4);       // 200 KB
    int*   perm  = (int*)carve(p, (size_t)Etot * 4);           // 6.6 MB
    // big region: binned (7.43 MB) dead after k_csr_local, then aliased by
    // a1s f16 (0.8) + a1d f32 (1.6) + h1 (6.4) written by k_mgemm1 afterwards.
    char*  big   = carve(p, 8800000);
    unsigned* binned = (unsigned*)big;
    _Float16* a1s    = (_Float16*)big;                           // 0.8 MB
    float*    a1d    = (float*)(big + 800000);                   // 1.6 MB
    __hip_bfloat16* h1   = (__hip_bfloat16*)(big + 2400000);     // 6.4 MB
    __hip_bfloat16* helu = (__hip_bfloat16*)carve(p, (size_t)NN * F1 * 2); // 6.4 MB
    _Float16* a2s = a1s;
    float*    a2d = a1d;
    __hip_bfloat16* h2 = h1;

    hipMemsetAsync(bcnt, 0, (size_t)NB * 4, stream);
    k_pre<<<1, 256, 0, stream>>>(x, ei, flags, W1, W2, W1p, W2p);

    int ab = (Etot + 4095) / 4096;
    k_bin_fine<<<ab, 256, 0, stream>>>(ei, E, Etot, bcnt, binned, flags);
    k_csr_local<<<NB, 256, 0, stream>>>(bcnt, binned, offs, perm);

    int ng = (NN + 63) / 64;
    k_mgemm1<<<ng, 256, 0, stream>>>(x, W1p, attS1, attD1, h1, a1s, a1d, flags);
    k_agg1<<<(NN + 3) / 4, 256, 0, stream>>>(offs, perm, h1, a1s, a1d, b1, helu, NN, flags);
    k_mgemm2<<<ng, 256, 0, stream>>>(helu, W2p, attS2, attD2, h2, a2s, a2d, flags);
    k_agg2<<<(NN + 3) / 4, 256, 0, stream>>>(offs, perm, h2, a2s, a2d, b2, linW, linb, d_out, NN, flags);
}